// Round 6
// baseline (284.396 us; speedup 1.0000x reference)
//
#include <hip/hip_runtime.h>
#include <math.h>

#define N_TS 4096
#define SEQ  168
#define HOR  24
#define T_ALL 192
#define F_INP 32
#define HID  64
#define NROW 192           // compacted gate rows: i(64) g(64) o(64)
#define HPAD 72            // padded fp16 row stride (144 B, 16B-aligned)
#define L2E  1.44269504089f

typedef _Float16 half8  __attribute__((ext_vector_type(8)));
typedef _Float16 half4  __attribute__((ext_vector_type(4)));
typedef float    floatx4 __attribute__((ext_vector_type(4)));

__device__ __forceinline__ float fexp(float x)  { return __expf(x); }
__device__ __forceinline__ float ex2(float x)   { return __builtin_amdgcn_exp2f(x); }
__device__ __forceinline__ float frcp(float x)  { return __builtin_amdgcn_rcpf(x); }
__device__ __forceinline__ float softplus_(float x) { return (x > 15.0f) ? x : __logf(1.0f + fexp(x)); }

// Gates arrive PRESCALED: i,o rows x(-log2e); g rows x(-2*log2e) — folded into
// weights/biases, so every sigmoid/tanh exp is a bare v_exp (2^x).
// h = sigm(o)*tanh(sigm(i)*tanh(g)), c0 = 0.
__device__ __forceinline__ float lstm_h(float ip, float gp, float op) {
    const float Ei = ex2(ip);
    const float Eg = ex2(gp);
    const float cc = (1.0f - Eg) * frcp((1.0f + Ei) * (1.0f + Eg));
    const float Ec = ex2(cc * (-2.0f * L2E));
    const float Eo = ex2(op);
    return (1.0f - Ec) * frcp((1.0f + Ec) * (1.0f + Eo));
}

__device__ __forceinline__ half8 cvt8(const float4 a, const float4 b) {
    half8 v;
    v[0]=(_Float16)a.x; v[1]=(_Float16)a.y; v[2]=(_Float16)a.z; v[3]=(_Float16)a.w;
    v[4]=(_Float16)b.x; v[5]=(_Float16)b.y; v[6]=(_Float16)b.z; v[7]=(_Float16)b.w;
    return v;
}

// ---------------------------------------------------------------------------
// prep: compacted (f dropped), PRESCALED weights in k-chunked fragment layout
//   W16f[ ((l*8 + kb)*192 + row)*8 + kp ],  k = kb*8+kp.  bsum prescaled too.
// ---------------------------------------------------------------------------
__global__ __launch_bounds__(256) void prep(
    const float* __restrict__ W_ih, const float* __restrict__ b_ih,
    const float* __restrict__ b_hh,
    _Float16* __restrict__ W16f, float* __restrict__ bsum)
{
    const int idx = blockIdx.x * 256 + threadIdx.x;
    for (int i = idx; i < 2 * 8 * NROW * 8; i += gridDim.x * 256) {
        const int kp  = i & 7;
        const int row = (i >> 3) % NROW;
        const int kb  = ((i >> 3) / NROW) & 7;
        const int l   = i / (8 * NROW * 8);
        const int sr  = (row < 64) ? row : row + 64;   // skip dead f rows
        const float sc = (row >= 64 && row < 128) ? (-2.0f * L2E) : (-L2E);
        W16f[i] = (_Float16)(W_ih[(l * 256 + sr) * HID + kb * 8 + kp] * sc);
    }
    for (int i = idx; i < 2 * NROW; i += gridDim.x * 256) {
        const int r = i % NROW;
        const int l = i / NROW;
        const int sr = (r < 64) ? r : r + 64;
        const float sc = (r >= 64 && r < 128) ? (-2.0f * L2E) : (-L2E);
        bsum[i] = (b_ih[l * 256 + sr] + b_hh[l * 256 + sr]) * sc;
    }
}

// ---------------------------------------------------------------------------
// cellsA: teacher-forced region. 16 cells/wave, 4 waves/block (64 cells).
// Layer-0 A-frags direct from global; per-layer weights LDS-staged (k-chunk,
// conflict-free b128); bias folded into MFMA C-init.
// ---------------------------------------------------------------------------
__global__ __launch_bounds__(256, 4) void cellsA(
    const float* __restrict__ X,
    const float* __restrict__ y,
    const float* __restrict__ W_embed,
    const float* __restrict__ b_embed,
    const _Float16* __restrict__ W16f,
    const float* __restrict__ bsum,
    const float* __restrict__ W_mu,
    const float* __restrict__ b_mu,
    const float* __restrict__ W_sigma,
    const float* __restrict__ b_sigma,
    float* __restrict__ out,
    float* __restrict__ lik167)
{
    __shared__ __align__(16) _Float16 Wl[NROW * HID];     // 24576 B, k-chunk
    __shared__ __align__(16) _Float16 Hx[4][16 * HPAD];   // 9216 B
    const int tid  = threadIdx.x;
    const int w    = tid >> 6;
    const int lane = tid & 63;
    const int quad = lane >> 4;
    const int ln   = lane & 15;
    const int cid0 = blockIdx.x * 64 + w * 16;
    const int cid  = cid0 + ln;

    // ---- layer-0 A-frags straight from global ----
    half8 afr0, afr1;
    {
        const float* xp = X + (size_t)cid * F_INP + quad * 8;
        const float4 xa = *(const float4*)xp;
        const float4 xb = *(const float4*)(xp + 4);
        afr0 = cvt8(xa, xb);
        const float yv = y[cid];
        const float4 wa = *(const float4*)(W_embed + quad * 8);
        const float4 wb = *(const float4*)(W_embed + quad * 8 + 4);
        const float4 ba = *(const float4*)(b_embed + quad * 8);
        const float4 bb = *(const float4*)(b_embed + quad * 8 + 4);
        afr1[0]=(_Float16)fmaf(yv, wa.x, ba.x); afr1[1]=(_Float16)fmaf(yv, wa.y, ba.y);
        afr1[2]=(_Float16)fmaf(yv, wa.z, ba.z); afr1[3]=(_Float16)fmaf(yv, wa.w, ba.w);
        afr1[4]=(_Float16)fmaf(yv, wb.x, bb.x); afr1[5]=(_Float16)fmaf(yv, wb.y, bb.y);
        afr1[6]=(_Float16)fmaf(yv, wb.z, bb.z); afr1[7]=(_Float16)fmaf(yv, wb.w, bb.w);
    }

    // ---- stage layer-0 weights ----
    #pragma unroll
    for (int c = 0; c < 6; ++c) {
        const int off = (c * 256 + tid) * 8;
        *(half8*)(Wl + off) = *(const half8*)(W16f + off);
    }
    __syncthreads();

    _Float16* hrow = Hx[w];
    {
        floatx4 acc[12];
        #pragma unroll
        for (int nt = 0; nt < 12; ++nt) {
            const float bv = bsum[nt * 16 + ln];
            acc[nt] = (floatx4){bv, bv, bv, bv};
        }
        const _Float16* bp = Wl + quad * 1536 + ln * 8;
        #pragma unroll
        for (int nt = 0; nt < 12; ++nt) {
            const half8 b0 = *(const half8*)(bp + nt * 128);
            const half8 b1 = *(const half8*)(bp + nt * 128 + 6144);
            acc[nt] = __builtin_amdgcn_mfma_f32_16x16x32_f16(afr0, b0, acc[nt], 0, 0, 0);
            acc[nt] = __builtin_amdgcn_mfma_f32_16x16x32_f16(afr1, b1, acc[nt], 0, 0, 0);
        }
        #pragma unroll
        for (int jt = 0; jt < 4; ++jt)
        #pragma unroll
        for (int r = 0; r < 4; ++r) {
            const float hh = lstm_h(acc[jt][r], acc[4 + jt][r], acc[8 + jt][r]);
            hrow[(quad * 4 + r) * HPAD + jt * 16 + ln] = (_Float16)hh;
        }
    }
    __syncthreads();   // all waves done reading Wl(layer0)

    // ---- stage layer-1 weights ----
    #pragma unroll
    for (int c = 0; c < 6; ++c) {
        const int off = (c * 256 + tid) * 8;
        *(half8*)(Wl + off) = *(const half8*)(W16f + 12288 + off);
    }
    __syncthreads();

    float hfin[4][4];
    {
        const half8 a0 = *(const half8*)(hrow + ln * HPAD + quad * 8);
        const half8 a1 = *(const half8*)(hrow + ln * HPAD + 32 + quad * 8);
        floatx4 acc[12];
        #pragma unroll
        for (int nt = 0; nt < 12; ++nt) {
            const float bv = bsum[NROW + nt * 16 + ln];
            acc[nt] = (floatx4){bv, bv, bv, bv};
        }
        const _Float16* bp = Wl + quad * 1536 + ln * 8;
        #pragma unroll
        for (int nt = 0; nt < 12; ++nt) {
            const half8 b0 = *(const half8*)(bp + nt * 128);
            const half8 b1 = *(const half8*)(bp + nt * 128 + 6144);
            acc[nt] = __builtin_amdgcn_mfma_f32_16x16x32_f16(a0, b0, acc[nt], 0, 0, 0);
            acc[nt] = __builtin_amdgcn_mfma_f32_16x16x32_f16(a1, b1, acc[nt], 0, 0, 0);
        }
        #pragma unroll
        for (int jt = 0; jt < 4; ++jt)
        #pragma unroll
        for (int r = 0; r < 4; ++r)
            hfin[jt][r] = lstm_h(acc[jt][r], acc[4 + jt][r], acc[8 + jt][r]);
    }

    // ---- heads ----
    float wmu[4], wsg[4];
    #pragma unroll
    for (int jt = 0; jt < 4; ++jt) {
        wmu[jt] = W_mu[jt * 16 + ln];
        wsg[jt] = W_sigma[jt * 16 + ln];
    }
    const float bmu = b_mu[0], bsg = b_sigma[0];
    float* mu_out = out + (size_t)N_TS * HOR;
    float* sg_out = mu_out + (size_t)N_TS * T_ALL;

    #pragma unroll
    for (int r = 0; r < 4; ++r) {
        float pm = 0.f, ps = 0.f;
        #pragma unroll
        for (int jt = 0; jt < 4; ++jt) {
            const float hr = fmaxf(hfin[jt][r], 0.0f);
            pm = fmaf(hr, wmu[jt], pm);
            ps = fmaf(hr, wsg[jt], ps);
        }
        #pragma unroll
        for (int off = 1; off < 16; off <<= 1) {
            pm += __shfl_xor(pm, off, 64);
            ps += __shfl_xor(ps, off, 64);
        }
        if (ln == 0) {
            const int cid2 = cid0 + quad * 4 + r;
            const int n = cid2 / SEQ;
            const int t = cid2 - n * SEQ;
            const float mu = pm + bmu;
            const float sg = softplus_(ps + bsg) + 1e-6f;
            mu_out[(size_t)n * T_ALL + t] = mu;
            sg_out[(size_t)n * T_ALL + t] = sg;
            if (t == SEQ - 1) {
                const float yv = y[cid2];
                const float d  = yv - mu;
                const float is = frcp(sg);
                const float lik = 0.39894228040143267f * is * fexp(-0.5f * d * d * is * is);
                out[(size_t)n * HOR] = lik;
                lik167[n] = lik;
            }
        }
    }
}

// ---------------------------------------------------------------------------
// cellsB: autoregressive region. ONE WAVE per block, 16 series end-to-end,
// ZERO barriers. mfma(W-frag, series-frag): C has series on ln, gate-rows on
// regs. W1/W2 + biases register-resident (~430 VGPR, 1 wave/SIMD by design);
// carry y in registers (each lane holds its col's y; quads end bit-identical
// after the xor-reduce, so no carry exchange); h1 bounced through a
// wave-private LDS slab (lgkmcnt only); stores fire-and-forget.
// ---------------------------------------------------------------------------
__global__ __launch_bounds__(64, 1) void cellsB(
    const float* __restrict__ Xf,
    const _Float16* __restrict__ W16f,
    const float* __restrict__ bsum,
    const float* __restrict__ W_embed,
    const float* __restrict__ b_embed,
    const float* __restrict__ W_mu,
    const float* __restrict__ b_mu,
    const float* __restrict__ W_sigma,
    const float* __restrict__ b_sigma,
    float* __restrict__ out,
    const float* __restrict__ lik167)
{
    __shared__ __align__(16) _Float16 slab[16][HPAD];   // h1 bounce, 2304 B
    const int lane = threadIdx.x;
    const int quad = lane >> 4;
    const int ln   = lane & 15;
    const int n0   = blockIdx.x * 16;

    // ---- persistent fragments: full W1 and W2 as A-operands ----
    half8 W1f[12][2], W2f[12][2];
    #pragma unroll
    for (int nt = 0; nt < 12; ++nt)
        #pragma unroll
        for (int kf = 0; kf < 2; ++kf) {
            const int kb = kf * 4 + quad;
            W1f[nt][kf] = *(const half8*)(W16f + ((size_t)kb * NROW + nt * 16 + ln) * 8);
            W2f[nt][kf] = *(const half8*)(W16f + 12288 + ((size_t)kb * NROW + nt * 16 + ln) * 8);
        }
    float4 b1v[12], b2v[12];          // gate-row = nt*16 + quad*4 + r
    #pragma unroll
    for (int nt = 0; nt < 12; ++nt) {
        b1v[nt] = *(const float4*)(bsum + nt * 16 + quad * 4);
        b2v[nt] = *(const float4*)(bsum + NROW + nt * 16 + quad * 4);
    }
    float we[8], be[8];
    #pragma unroll
    for (int e = 0; e < 8; ++e) {
        we[e] = W_embed[quad * 8 + e];
        be[e] = b_embed[quad * 8 + e];
    }
    float4 wmuv[4], wsgv[4];          // unit = jt*16 + quad*4 + r
    #pragma unroll
    for (int jt = 0; jt < 4; ++jt) {
        wmuv[jt] = *(const float4*)(W_mu + jt * 16 + quad * 4);
        wsgv[jt] = *(const float4*)(W_sigma + jt * 16 + quad * 4);
    }
    const float bmu = b_mu[0], bsg = b_sigma[0];

    float yv = lik167[n0 + ln];       // carry for series ln (all quads)

    float* mu_out = out + (size_t)N_TS * HOR;
    float* sg_out = mu_out + (size_t)N_TS * T_ALL;

    const float* xp = Xf + (size_t)(n0 + ln) * HOR * F_INP + quad * 8;
    float4 xa = *(const float4*)xp;
    float4 xb = *(const float4*)(xp + 4);

    #pragma unroll 1
    for (int s = 0; s < HOR; ++s) {
        const half8 xf0 = cvt8(xa, xb);
        if (s < HOR - 1) {
            xa = *(const float4*)(xp + (s + 1) * F_INP);
            xb = *(const float4*)(xp + (s + 1) * F_INP + 4);
        }
        half8 xf1;                    // yembed slice for this lane's k-range
        #pragma unroll
        for (int e = 0; e < 8; ++e)
            xf1[e] = (_Float16)fmaf(yv, we[e], be[e]);

        // ---- layer 1: 24 MFMAs, C = series(ln) x gate-rows(regs) ----
        floatx4 acc[12];
        #pragma unroll
        for (int nt = 0; nt < 12; ++nt) {
            acc[nt] = (floatx4){b1v[nt].x, b1v[nt].y, b1v[nt].z, b1v[nt].w};
            acc[nt] = __builtin_amdgcn_mfma_f32_16x16x32_f16(W1f[nt][0], xf0, acc[nt], 0, 0, 0);
            acc[nt] = __builtin_amdgcn_mfma_f32_16x16x32_f16(W1f[nt][1], xf1, acc[nt], 0, 0, 0);
        }

        // ---- act L1 -> wave-private slab (no barrier) ----
        #pragma unroll
        for (int jt = 0; jt < 4; ++jt) {
            half4 hp;
            #pragma unroll
            for (int r = 0; r < 4; ++r)
                hp[r] = (_Float16)lstm_h(acc[jt][r], acc[4 + jt][r], acc[8 + jt][r]);
            *(half4*)(&slab[ln][jt * 16 + quad * 4]) = hp;
        }
        const half8 a0 = *(const half8*)(&slab[ln][quad * 8]);
        const half8 a1 = *(const half8*)(&slab[ln][32 + quad * 8]);

        // ---- layer 2: 24 MFMAs ----
        #pragma unroll
        for (int nt = 0; nt < 12; ++nt) {
            acc[nt] = (floatx4){b2v[nt].x, b2v[nt].y, b2v[nt].z, b2v[nt].w};
            acc[nt] = __builtin_amdgcn_mfma_f32_16x16x32_f16(W2f[nt][0], a0, acc[nt], 0, 0, 0);
            acc[nt] = __builtin_amdgcn_mfma_f32_16x16x32_f16(W2f[nt][1], a1, acc[nt], 0, 0, 0);
        }

        // ---- act L2 + heads ----
        float pm = 0.f, ps = 0.f;
        #pragma unroll
        for (int jt = 0; jt < 4; ++jt)
        #pragma unroll
        for (int r = 0; r < 4; ++r) {
            const float hh = lstm_h(acc[jt][r], acc[4 + jt][r], acc[8 + jt][r]);
            const float hr = fmaxf(hh, 0.0f);
            pm = fmaf(hr, ((const float*)&wmuv[jt])[r], pm);
            ps = fmaf(hr, ((const float*)&wsgv[jt])[r], ps);
        }
        pm += __shfl_xor(pm, 16, 64);  pm += __shfl_xor(pm, 32, 64);
        ps += __shfl_xor(ps, 16, 64);  ps += __shfl_xor(ps, 32, 64);

        const float mu = pm + bmu;
        const float sg = softplus_(ps + bsg) + 1e-6f;
        const float d  = yv - mu;
        const float is = frcp(sg);
        const float lik = 0.39894228040143267f * is * fexp(-0.5f * d * d * is * is);

        if (quad == 0) {
            const int nn = n0 + ln;
            const int t  = SEQ + s;
            mu_out[(size_t)nn * T_ALL + t] = mu;
            sg_out[(size_t)nn * T_ALL + t] = sg;
            if (s < HOR - 1) out[(size_t)nn * HOR + s + 1] = lik;
        }
        yv = lik;                     // bit-identical across quads
    }
}

extern "C" void kernel_launch(void* const* d_in, const int* in_sizes, int n_in,
                              void* d_out, int out_size, void* d_ws, size_t ws_size,
                              hipStream_t stream) {
    const float* X       = (const float*)d_in[0];
    const float* y       = (const float*)d_in[1];
    const float* Xf      = (const float*)d_in[2];
    const float* W_embed = (const float*)d_in[3];
    const float* b_embed = (const float*)d_in[4];
    const float* W_ih    = (const float*)d_in[5];
    const float* b_ih    = (const float*)d_in[6];
    const float* b_hh    = (const float*)d_in[7];
    const float* W_mu    = (const float*)d_in[8];
    const float* b_mu    = (const float*)d_in[9];
    const float* W_sigma = (const float*)d_in[10];
    const float* b_sigma = (const float*)d_in[11];

    float* out = (float*)d_out;
    // ws: lik167(16384 B) | W16f(49152 B) | bsum(1536 B)
    float*     lik167 = (float*)d_ws;
    _Float16*  W16f   = (_Float16*)((char*)d_ws + 16384);
    float*     bsum   = (float*)((char*)d_ws + 16384 + 49152);

    prep<<<96, 256, 0, stream>>>(W_ih, b_ih, b_hh, W16f, bsum);

    cellsA<<<(N_TS * SEQ) / 64, 256, 0, stream>>>(
        X, y, W_embed, b_embed, W16f, bsum,
        W_mu, b_mu, W_sigma, b_sigma, out, lik167);

    cellsB<<<N_TS / 16, 64, 0, stream>>>(
        Xf, W16f, bsum, W_embed, b_embed,
        W_mu, b_mu, W_sigma, b_sigma, out, lik167);
}

// Round 7
// 282.362 us; speedup vs baseline: 1.0072x; 1.0072x over previous
//
#include <hip/hip_runtime.h>
#include <math.h>

#define N_TS 4096
#define SEQ  168
#define HOR  24
#define T_ALL 192
#define F_INP 32
#define HID  64
#define NROW 192           // compacted gate rows: i(64) g(64) o(64)
#define L2E  1.44269504089f

typedef _Float16 half8  __attribute__((ext_vector_type(8)));
typedef _Float16 half4  __attribute__((ext_vector_type(4)));
typedef float    floatx4 __attribute__((ext_vector_type(4)));

__device__ __forceinline__ float fexp(float x)  { return __expf(x); }
__device__ __forceinline__ float ex2(float x)   { return __builtin_amdgcn_exp2f(x); }
__device__ __forceinline__ float frcp(float x)  { return __builtin_amdgcn_rcpf(x); }
__device__ __forceinline__ float softplus_(float x) { return (x > 15.0f) ? x : __logf(1.0f + fexp(x)); }

// Gates arrive PRESCALED: i,o rows x(-log2e); g rows x(-2*log2e) — folded into
// weights/biases, so every sigmoid/tanh exp is a bare v_exp (2^x).
__device__ __forceinline__ float lstm_h(float ip, float gp, float op) {
    const float Ei = ex2(ip);
    const float Eg = ex2(gp);
    const float cc = (1.0f - Eg) * frcp((1.0f + Ei) * (1.0f + Eg));
    const float Ec = ex2(cc * (-2.0f * L2E));
    const float Eo = ex2(op);
    return (1.0f - Ec) * frcp((1.0f + Ec) * (1.0f + Eo));
}

__device__ __forceinline__ half8 cvt8(const float4 a, const float4 b) {
    half8 v;
    v[0]=(_Float16)a.x; v[1]=(_Float16)a.y; v[2]=(_Float16)a.z; v[3]=(_Float16)a.w;
    v[4]=(_Float16)b.x; v[5]=(_Float16)b.y; v[6]=(_Float16)b.z; v[7]=(_Float16)b.w;
    return v;
}

// ---------------------------------------------------------------------------
// prep: compacted (f dropped), PRESCALED weights in k-chunked fragment layout
//   W16f[ ((l*8 + kb)*192 + row)*8 + kp ],  k = kb*8+kp.  bsum prescaled too.
// ---------------------------------------------------------------------------
__global__ __launch_bounds__(256) void prep(
    const float* __restrict__ W_ih, const float* __restrict__ b_ih,
    const float* __restrict__ b_hh,
    _Float16* __restrict__ W16f, float* __restrict__ bsum)
{
    const int idx = blockIdx.x * 256 + threadIdx.x;
    for (int i = idx; i < 2 * 8 * NROW * 8; i += gridDim.x * 256) {
        const int kp  = i & 7;
        const int row = (i >> 3) % NROW;
        const int kb  = ((i >> 3) / NROW) & 7;
        const int l   = i / (8 * NROW * 8);
        const int sr  = (row < 64) ? row : row + 64;   // skip dead f rows
        const float sc = (row >= 64 && row < 128) ? (-2.0f * L2E) : (-L2E);
        W16f[i] = (_Float16)(W_ih[(l * 256 + sr) * HID + kb * 8 + kp] * sc);
    }
    for (int i = idx; i < 2 * NROW; i += gridDim.x * 256) {
        const int r = i % NROW;
        const int l = i / NROW;
        const int sr = (r < 64) ? r : r + 64;
        const float sc = (r >= 64 && r < 128) ? (-2.0f * L2E) : (-L2E);
        bsum[i] = (b_ih[l * 256 + sr] + b_hh[l * 256 + sr]) * sc;
    }
}

// ---------------------------------------------------------------------------
// cellsA: teacher-forced region. 16 cells/wave, 4 waves/block (64 cells).
// LDS = 24576 (Wl) + 8192 (Hx, XOR-swizzled, no pad) = 32768 B -> 5 blocks/CU.
// Gate-tiles processed jt-by-jt (12 live acc regs -> VGPR accumulator).
// ---------------------------------------------------------------------------
__global__ __launch_bounds__(256, 5) void cellsA(
    const float* __restrict__ X,
    const float* __restrict__ y,
    const float* __restrict__ W_embed,
    const float* __restrict__ b_embed,
    const _Float16* __restrict__ W16f,
    const float* __restrict__ bsum,
    const float* __restrict__ W_mu,
    const float* __restrict__ b_mu,
    const float* __restrict__ W_sigma,
    const float* __restrict__ b_sigma,
    float* __restrict__ out,
    float* __restrict__ lik167)
{
    __shared__ __align__(16) _Float16 Wl[NROW * HID];   // 24576 B, k-chunk
    __shared__ __align__(16) _Float16 Hx[4][16 * 64];   // 8192 B, swizzled
    const int tid  = threadIdx.x;
    const int w    = tid >> 6;
    const int lane = tid & 63;
    const int quad = lane >> 4;
    const int ln   = lane & 15;
    const int cid0 = blockIdx.x * 64 + w * 16;
    const int cid  = cid0 + ln;

    // ---- layer-0 A-frags straight from global ----
    half8 afr0, afr1;
    {
        const float* xp = X + (size_t)cid * F_INP + quad * 8;
        const float4 xa = *(const float4*)xp;
        const float4 xb = *(const float4*)(xp + 4);
        afr0 = cvt8(xa, xb);
        const float yv = y[cid];
        const float4 wa = *(const float4*)(W_embed + quad * 8);
        const float4 wb = *(const float4*)(W_embed + quad * 8 + 4);
        const float4 ba = *(const float4*)(b_embed + quad * 8);
        const float4 bb = *(const float4*)(b_embed + quad * 8 + 4);
        afr1[0]=(_Float16)fmaf(yv, wa.x, ba.x); afr1[1]=(_Float16)fmaf(yv, wa.y, ba.y);
        afr1[2]=(_Float16)fmaf(yv, wa.z, ba.z); afr1[3]=(_Float16)fmaf(yv, wa.w, ba.w);
        afr1[4]=(_Float16)fmaf(yv, wb.x, bb.x); afr1[5]=(_Float16)fmaf(yv, wb.y, bb.y);
        afr1[6]=(_Float16)fmaf(yv, wb.z, bb.z); afr1[7]=(_Float16)fmaf(yv, wb.w, bb.w);
    }

    // ---- stage layer-0 weights ----
    #pragma unroll
    for (int c = 0; c < 6; ++c) {
        const int off = (c * 256 + tid) * 8;
        *(half8*)(Wl + off) = *(const half8*)(W16f + off);
    }
    __syncthreads();

    _Float16* hrow = Hx[w];
    {
        const _Float16* bp = Wl + quad * 1536 + ln * 8;
        #pragma unroll
        for (int jt = 0; jt < 4; ++jt) {
            const float bi = bsum[jt * 16 + ln];
            const float bg = bsum[(4 + jt) * 16 + ln];
            const float bo = bsum[(8 + jt) * 16 + ln];
            floatx4 ai = (floatx4){bi, bi, bi, bi};
            floatx4 ag = (floatx4){bg, bg, bg, bg};
            floatx4 ao = (floatx4){bo, bo, bo, bo};
            ai = __builtin_amdgcn_mfma_f32_16x16x32_f16(afr0, *(const half8*)(bp + jt * 128),            ai, 0, 0, 0);
            ai = __builtin_amdgcn_mfma_f32_16x16x32_f16(afr1, *(const half8*)(bp + jt * 128 + 6144),     ai, 0, 0, 0);
            ag = __builtin_amdgcn_mfma_f32_16x16x32_f16(afr0, *(const half8*)(bp + (4 + jt) * 128),      ag, 0, 0, 0);
            ag = __builtin_amdgcn_mfma_f32_16x16x32_f16(afr1, *(const half8*)(bp + (4 + jt) * 128 + 6144), ag, 0, 0, 0);
            ao = __builtin_amdgcn_mfma_f32_16x16x32_f16(afr0, *(const half8*)(bp + (8 + jt) * 128),      ao, 0, 0, 0);
            ao = __builtin_amdgcn_mfma_f32_16x16x32_f16(afr1, *(const half8*)(bp + (8 + jt) * 128 + 6144), ao, 0, 0, 0);
            #pragma unroll
            for (int r = 0; r < 4; ++r) {
                const float hh = lstm_h(ai[r], ag[r], ao[r]);
                const int row = quad * 4 + r;
                const int col = jt * 16 + ln;
                hrow[row * 64 + (((col >> 3) ^ (row & 7)) << 3) + (col & 7)] = (_Float16)hh;
            }
        }
    }

    // A-frags for layer 1 from own swizzled slab (same wave; lgkm-ordered)
    const half8 a0 = *(const half8*)(hrow + ln * 64 + ((quad ^ (ln & 7)) << 3));
    const half8 a1 = *(const half8*)(hrow + ln * 64 + (((4 + quad) ^ (ln & 7)) << 3));

    __syncthreads();   // all waves done reading Wl(layer0)
    #pragma unroll
    for (int c = 0; c < 6; ++c) {
        const int off = (c * 256 + tid) * 8;
        *(half8*)(Wl + off) = *(const half8*)(W16f + 12288 + off);
    }
    __syncthreads();

    float hfin[4][4];
    {
        const _Float16* bp = Wl + quad * 1536 + ln * 8;
        #pragma unroll
        for (int jt = 0; jt < 4; ++jt) {
            const float bi = bsum[NROW + jt * 16 + ln];
            const float bg = bsum[NROW + (4 + jt) * 16 + ln];
            const float bo = bsum[NROW + (8 + jt) * 16 + ln];
            floatx4 ai = (floatx4){bi, bi, bi, bi};
            floatx4 ag = (floatx4){bg, bg, bg, bg};
            floatx4 ao = (floatx4){bo, bo, bo, bo};
            ai = __builtin_amdgcn_mfma_f32_16x16x32_f16(a0, *(const half8*)(bp + jt * 128),            ai, 0, 0, 0);
            ai = __builtin_amdgcn_mfma_f32_16x16x32_f16(a1, *(const half8*)(bp + jt * 128 + 6144),     ai, 0, 0, 0);
            ag = __builtin_amdgcn_mfma_f32_16x16x32_f16(a0, *(const half8*)(bp + (4 + jt) * 128),      ag, 0, 0, 0);
            ag = __builtin_amdgcn_mfma_f32_16x16x32_f16(a1, *(const half8*)(bp + (4 + jt) * 128 + 6144), ag, 0, 0, 0);
            ao = __builtin_amdgcn_mfma_f32_16x16x32_f16(a0, *(const half8*)(bp + (8 + jt) * 128),      ao, 0, 0, 0);
            ao = __builtin_amdgcn_mfma_f32_16x16x32_f16(a1, *(const half8*)(bp + (8 + jt) * 128 + 6144), ao, 0, 0, 0);
            #pragma unroll
            for (int r = 0; r < 4; ++r)
                hfin[jt][r] = lstm_h(ai[r], ag[r], ao[r]);
        }
    }

    // ---- heads ----
    float wmu[4], wsg[4];
    #pragma unroll
    for (int jt = 0; jt < 4; ++jt) {
        wmu[jt] = W_mu[jt * 16 + ln];
        wsg[jt] = W_sigma[jt * 16 + ln];
    }
    const float bmu = b_mu[0], bsg = b_sigma[0];
    float* mu_out = out + (size_t)N_TS * HOR;
    float* sg_out = mu_out + (size_t)N_TS * T_ALL;

    #pragma unroll
    for (int r = 0; r < 4; ++r) {
        float pm = 0.f, ps = 0.f;
        #pragma unroll
        for (int jt = 0; jt < 4; ++jt) {
            const float hr = fmaxf(hfin[jt][r], 0.0f);
            pm = fmaf(hr, wmu[jt], pm);
            ps = fmaf(hr, wsg[jt], ps);
        }
        #pragma unroll
        for (int off = 1; off < 16; off <<= 1) {
            pm += __shfl_xor(pm, off, 64);
            ps += __shfl_xor(ps, off, 64);
        }
        if (ln == 0) {
            const int cid2 = cid0 + quad * 4 + r;
            const int n = cid2 / SEQ;
            const int t = cid2 - n * SEQ;
            const float mu = pm + bmu;
            const float sg = softplus_(ps + bsg) + 1e-6f;
            mu_out[(size_t)n * T_ALL + t] = mu;
            sg_out[(size_t)n * T_ALL + t] = sg;
            if (t == SEQ - 1) {
                const float yv = y[cid2];
                const float d  = yv - mu;
                const float is = frcp(sg);
                const float lik = 0.39894228040143267f * is * fexp(-0.5f * d * d * is * is);
                out[(size_t)n * HOR] = lik;
                lik167[n] = lik;
            }
        }
    }
}

// ---------------------------------------------------------------------------
// cellsB: autoregressive region. ONE WAVE per block, 16 series, zero barriers.
// ANTI-SPILL: only W1 fragments + layer-1 biases persist in registers (~150);
// W2 fragments and all other biases live in LDS, read per step (conflict-free
// ds_read_b128, overlapped with MFMA issue). Carry stays in registers.
// ---------------------------------------------------------------------------
__global__ __launch_bounds__(64, 1) void cellsB(
    const float* __restrict__ Xf,
    const _Float16* __restrict__ W16f,
    const float* __restrict__ bsum,
    const float* __restrict__ W_embed,
    const float* __restrict__ b_embed,
    const float* __restrict__ W_mu,
    const float* __restrict__ b_mu,
    const float* __restrict__ W_sigma,
    const float* __restrict__ b_sigma,
    float* __restrict__ out,
    const float* __restrict__ lik167)
{
    __shared__ __align__(16) _Float16 W2l[12288];      // 24576 B, k-chunk
    __shared__ __align__(16) float    b2l[NROW];       // 768 B
    __shared__ __align__(16) _Float16 slab[16 * 72];   // 2304 B (padded)
    const int lane = threadIdx.x;
    const int quad = lane >> 4;
    const int ln   = lane & 15;
    const int n0   = blockIdx.x * 16;

    // ---- stage W2 + layer-2 biases into LDS (single wave; lgkm-ordered) ----
    #pragma unroll
    for (int c = 0; c < 24; ++c) {
        const int off = (c * 64 + lane) * 8;
        *(half8*)(W2l + off) = *(const half8*)(W16f + 12288 + off);
    }
    #pragma unroll
    for (int c = 0; c < 3; ++c)
        b2l[c * 64 + lane] = bsum[NROW + c * 64 + lane];
    __builtin_amdgcn_s_waitcnt(0);

    // ---- persistent registers: layer-1 only ----
    half8 W1f[12][2];
    #pragma unroll
    for (int nt = 0; nt < 12; ++nt)
        #pragma unroll
        for (int kf = 0; kf < 2; ++kf)
            W1f[nt][kf] = *(const half8*)(W16f + ((size_t)(kf * 4 + quad) * NROW + nt * 16 + ln) * 8);
    float4 b1v[12];                    // gate-row = nt*16 + quad*4 + r
    #pragma unroll
    for (int nt = 0; nt < 12; ++nt)
        b1v[nt] = *(const float4*)(bsum + nt * 16 + quad * 4);
    float we[8], be[8];
    #pragma unroll
    for (int e = 0; e < 8; ++e) {
        we[e] = W_embed[quad * 8 + e];
        be[e] = b_embed[quad * 8 + e];
    }
    float4 wmuv[4], wsgv[4];           // unit = jt*16 + quad*4 + r
    #pragma unroll
    for (int jt = 0; jt < 4; ++jt) {
        wmuv[jt] = *(const float4*)(W_mu + jt * 16 + quad * 4);
        wsgv[jt] = *(const float4*)(W_sigma + jt * 16 + quad * 4);
    }
    const float bmu = b_mu[0], bsg = b_sigma[0];

    float yv = lik167[n0 + ln];        // carry for series ln (all quads)

    float* mu_out = out + (size_t)N_TS * HOR;
    float* sg_out = mu_out + (size_t)N_TS * T_ALL;

    const float* xp = Xf + (size_t)(n0 + ln) * HOR * F_INP + quad * 8;
    float4 xa = *(const float4*)xp;
    float4 xb = *(const float4*)(xp + 4);

    #pragma unroll 1
    for (int s = 0; s < HOR; ++s) {
        const half8 xf0 = cvt8(xa, xb);
        if (s < HOR - 1) {
            xa = *(const float4*)(xp + (s + 1) * F_INP);
            xb = *(const float4*)(xp + (s + 1) * F_INP + 4);
        }
        half8 xf1;                     // yembed slice for this lane's k-range
        #pragma unroll
        for (int e = 0; e < 8; ++e)
            xf1[e] = (_Float16)fmaf(yv, we[e], be[e]);

        // ---- layer 1: 24 MFMAs, C = gate-rows(regs) x series(ln) ----
        floatx4 acc[12];
        #pragma unroll
        for (int nt = 0; nt < 12; ++nt) {
            acc[nt] = (floatx4){b1v[nt].x, b1v[nt].y, b1v[nt].z, b1v[nt].w};
            acc[nt] = __builtin_amdgcn_mfma_f32_16x16x32_f16(W1f[nt][0], xf0, acc[nt], 0, 0, 0);
            acc[nt] = __builtin_amdgcn_mfma_f32_16x16x32_f16(W1f[nt][1], xf1, acc[nt], 0, 0, 0);
        }

        // ---- act L1 -> slab (unit = jt*16+quad*4+r, series = ln) ----
        #pragma unroll
        for (int jt = 0; jt < 4; ++jt) {
            half4 hp;
            #pragma unroll
            for (int r = 0; r < 4; ++r)
                hp[r] = (_Float16)lstm_h(acc[jt][r], acc[4 + jt][r], acc[8 + jt][r]);
            *(half4*)(&slab[ln * 72 + jt * 16 + quad * 4]) = hp;
        }
        const half8 a0 = *(const half8*)(&slab[ln * 72 + quad * 8]);
        const half8 a1 = *(const half8*)(&slab[ln * 72 + 32 + quad * 8]);

        // ---- layer 2: W2 frags + biases from LDS ----
        #pragma unroll
        for (int nt = 0; nt < 12; ++nt) {
            const floatx4 bi = *(const floatx4*)(b2l + nt * 16 + quad * 4);
            floatx4 a = bi;
            a = __builtin_amdgcn_mfma_f32_16x16x32_f16(
                    *(const half8*)(W2l + ((size_t)quad * NROW + nt * 16 + ln) * 8), a0, a, 0, 0, 0);
            a = __builtin_amdgcn_mfma_f32_16x16x32_f16(
                    *(const half8*)(W2l + ((size_t)(4 + quad) * NROW + nt * 16 + ln) * 8), a1, a, 0, 0, 0);
            acc[nt] = a;
        }

        // ---- act L2 + heads ----
        float pm = 0.f, ps = 0.f;
        #pragma unroll
        for (int jt = 0; jt < 4; ++jt)
        #pragma unroll
        for (int r = 0; r < 4; ++r) {
            const float hh = lstm_h(acc[jt][r], acc[4 + jt][r], acc[8 + jt][r]);
            const float hr = fmaxf(hh, 0.0f);
            pm = fmaf(hr, ((const float*)&wmuv[jt])[r], pm);
            ps = fmaf(hr, ((const float*)&wsgv[jt])[r], ps);
        }
        pm += __shfl_xor(pm, 16, 64);  pm += __shfl_xor(pm, 32, 64);
        ps += __shfl_xor(ps, 16, 64);  ps += __shfl_xor(ps, 32, 64);

        const float mu = pm + bmu;
        const float sg = softplus_(ps + bsg) + 1e-6f;
        const float d  = yv - mu;
        const float is = frcp(sg);
        const float lik = 0.39894228040143267f * is * fexp(-0.5f * d * d * is * is);

        if (quad == 0) {
            const int nn = n0 + ln;
            const int t  = SEQ + s;
            mu_out[(size_t)nn * T_ALL + t] = mu;
            sg_out[(size_t)nn * T_ALL + t] = sg;
            if (s < HOR - 1) out[(size_t)nn * HOR + s + 1] = lik;
        }
        yv = lik;                      // bit-identical across quads
    }
}

extern "C" void kernel_launch(void* const* d_in, const int* in_sizes, int n_in,
                              void* d_out, int out_size, void* d_ws, size_t ws_size,
                              hipStream_t stream) {
    const float* X       = (const float*)d_in[0];
    const float* y       = (const float*)d_in[1];
    const float* Xf      = (const float*)d_in[2];
    const float* W_embed = (const float*)d_in[3];
    const float* b_embed = (const float*)d_in[4];
    const float* W_ih    = (const float*)d_in[5];
    const float* b_ih    = (const float*)d_in[6];
    const float* b_hh    = (const float*)d_in[7];
    const float* W_mu    = (const float*)d_in[8];
    const float* b_mu    = (const float*)d_in[9];
    const float* W_sigma = (const float*)d_in[10];
    const float* b_sigma = (const float*)d_in[11];

    float* out = (float*)d_out;
    // ws: lik167(16384 B) | W16f(49152 B) | bsum(1536 B)
    float*     lik167 = (float*)d_ws;
    _Float16*  W16f   = (_Float16*)((char*)d_ws + 16384);
    float*     bsum   = (float*)((char*)d_ws + 16384 + 49152);

    prep<<<96, 256, 0, stream>>>(W_ih, b_ih, b_hh, W16f, bsum);

    cellsA<<<(N_TS * SEQ) / 64, 256, 0, stream>>>(
        X, y, W_embed, b_embed, W16f, bsum,
        W_mu, b_mu, W_sigma, b_sigma, out, lik167);

    cellsB<<<N_TS / 16, 64, 0, stream>>>(
        Xf, W16f, bsum, W_embed, b_embed,
        W_mu, b_mu, W_sigma, b_sigma, out, lik167);
}